// Round 2
// baseline (379.871 us; speedup 1.0000x reference)
//
#include <hip/hip_runtime.h>

#define D   256
#define NP  512
#define BG  512
#define K   32
#define D4  (D/4)   // 64 float4 per row

// One block (256 threads = 4 waves) per graph:
//   phase 1: gate = feat @ w^T + b  (wave-per-row, float4 loads, shfl reduce)
//   phase 2: block softmax (max, exp, sum) -> p = e/denom, exactly as reference
//   phase 3: bitonic sort of 512 packed uint64 keys (desc p, asc idx tie-break)
//   phase 4: gather top-32 rows -> out[g,:,:]
__global__ __launch_bounds__(256) void fused_pool_kernel(const float* __restrict__ feat,
                                                         const float* __restrict__ w,
                                                         const float* __restrict__ b,
                                                         float* __restrict__ out) {
    __shared__ float sval[NP];
    __shared__ unsigned long long skey[NP];
    __shared__ float red[4];
    __shared__ float s_bcast;

    const int g    = blockIdx.x;
    const int tid  = threadIdx.x;
    const int lane = tid & 63;
    const int wid  = tid >> 6;

    const float4  w4   = ((const float4*)w)[lane];
    const float   bias = b[0];
    const float4* f4   = (const float4*)feat + (size_t)g * NP * D4;

    // ---- phase 1: gates, 128 rows per wave, unroll 4 for MLP/ILP ----
    const int rbase = wid * 128;
    for (int i = 0; i < 128; i += 4) {
        const int r = rbase + i;
        float4 a0 = f4[(size_t)(r + 0) * D4 + lane];
        float4 a1 = f4[(size_t)(r + 1) * D4 + lane];
        float4 a2 = f4[(size_t)(r + 2) * D4 + lane];
        float4 a3 = f4[(size_t)(r + 3) * D4 + lane];
        float s0 = a0.x * w4.x + a0.y * w4.y + a0.z * w4.z + a0.w * w4.w;
        float s1 = a1.x * w4.x + a1.y * w4.y + a1.z * w4.z + a1.w * w4.w;
        float s2 = a2.x * w4.x + a2.y * w4.y + a2.z * w4.z + a2.w * w4.w;
        float s3 = a3.x * w4.x + a3.y * w4.y + a3.z * w4.z + a3.w * w4.w;
        #pragma unroll
        for (int off = 32; off; off >>= 1) {
            s0 += __shfl_xor(s0, off, 64);
            s1 += __shfl_xor(s1, off, 64);
            s2 += __shfl_xor(s2, off, 64);
            s3 += __shfl_xor(s3, off, 64);
        }
        if (lane == 0) {
            sval[r + 0] = s0 + bias;
            sval[r + 1] = s1 + bias;
            sval[r + 2] = s2 + bias;
            sval[r + 3] = s3 + bias;
        }
    }
    __syncthreads();

    const float v0 = sval[tid];
    const float v1 = sval[tid + 256];

    // ---- phase 2a: block max ----
    float m = fmaxf(v0, v1);
    #pragma unroll
    for (int off = 32; off; off >>= 1)
        m = fmaxf(m, __shfl_xor(m, off, 64));
    if (lane == 0) red[wid] = m;
    __syncthreads();
    if (tid == 0) s_bcast = fmaxf(fmaxf(red[0], red[1]), fmaxf(red[2], red[3]));
    __syncthreads();
    const float gmax = s_bcast;

    // ---- phase 2b: exp + block sum ----
    const float e0 = expf(v0 - gmax);
    const float e1 = expf(v1 - gmax);
    float s = e0 + e1;
    #pragma unroll
    for (int off = 32; off; off >>= 1)
        s += __shfl_xor(s, off, 64);
    __syncthreads();               // tid0's reads of red (max phase) must finish
    if (lane == 0) red[wid] = s;
    __syncthreads();
    if (tid == 0) s_bcast = (red[0] + red[1]) + (red[2] + red[3]);
    __syncthreads();
    const float denom = s_bcast;

    // ---- pack sort keys: p>0 so float bits are order-monotone; low 32 bits
    // hold (NP-1-idx) so equal p orders by ascending idx under descending sort
    const float p0 = e0 / denom;
    const float p1 = e1 / denom;
    skey[tid] = ((unsigned long long)__float_as_uint(p0) << 32)
              | (unsigned)(NP - 1 - tid);
    skey[tid + 256] = ((unsigned long long)__float_as_uint(p1) << 32)
                    | (unsigned)(NP - 1 - (tid + 256));
    __syncthreads();

    // ---- phase 3: bitonic sort, descending by uint64 key ----
    for (int k = 2; k <= NP; k <<= 1) {
        for (int j = k >> 1; j > 0; j >>= 1) {
            #pragma unroll
            for (int rep = 0; rep < 2; ++rep) {
                int t = tid + rep * 256;
                int ixj = t ^ j;
                if (ixj > t) {
                    unsigned long long ka = skey[t], kb = skey[ixj];
                    bool b_first = kb > ka;                       // descending
                    bool do_swap = ((t & k) == 0) ? b_first : !b_first;
                    if (do_swap) { skey[t] = kb; skey[ixj] = ka; }
                }
            }
            __syncthreads();
        }
    }

    // ---- phase 4: gather top-K rows (L2/L3-warm) -> out[g, r, :] ----
    float4* o4 = (float4*)out + (size_t)g * K * D4;
    #pragma unroll
    for (int q = tid; q < K * D4; q += 256) {
        int r = q >> 6;                                   // rank 0..31
        int c = q & 63;                                   // float4 column
        int row = NP - 1 - (int)(unsigned)(skey[r] & 0xffffffffULL);
        o4[q] = f4[(size_t)row * D4 + c];
    }
}

extern "C" void kernel_launch(void* const* d_in, const int* in_sizes, int n_in,
                              void* d_out, int out_size, void* d_ws, size_t ws_size,
                              hipStream_t stream) {
    const float* feat = (const float*)d_in[0];   // (N, D)
    const float* w    = (const float*)d_in[1];   // (1, D)
    const float* b    = (const float*)d_in[2];   // (1,)
    // d_in[3] = segment_ids: fixed repeat(arange(B), NP) -> implicit

    fused_pool_kernel<<<BG, 256, 0, stream>>>(feat, w, b, (float*)d_out);
}